// Round 11
// baseline (41.072 us; speedup 1.0000x reference)
//
#include <hip/hip_runtime.h>

// anchors: (8192, 8, 768) fp32 = [n=8192 rows][COLS=6144 cols]
// loss = (2*dot(colsum,colsum) - 2*n*sum(a^2)) / sqrt(768) / 64
//
// R11: identical to R10 except pass1 loads are NON-TEMPORAL (isolated;
// R3 bundled nt with device fences which caused that regression).
// Rationale: streaming 201MB through the 256MB L3 thrashes (R3 counters:
// only ~50% L3 hit) and the allocate-on-stream path measured 5.45 TB/s;
// a clean nt HBM stream should match the fill kernels' ~7 TB/s.

typedef float f32x4 __attribute__((ext_vector_type(4)));

constexpr int COLS   = 6144;
constexpr int COLS4  = COLS / 4;           // 1536
constexpr int BLK    = 256;
constexpr int STRIPS = COLS4 / BLK;        // 6
constexpr int RPC    = 64;
constexpr int CHUNKS = 8192 / RPC;         // 128
constexpr int NBLK1  = STRIPS * CHUNKS;    // 768
constexpr int NBLK2  = COLS4 / 64;         // 24

// ws floats: partial f32x4[CHUNKS][COLS4] (3 MB) | ssq_arr[NBLK1] | dotacc | cnt
constexpr size_t PART_F = (size_t)CHUNKS * COLS4 * 4;
constexpr size_t SSQ_F  = PART_F;
constexpr size_t DOTA_F = PART_F + NBLK1;
constexpr size_t CNT_F  = DOTA_F + 1;

__global__ void __launch_bounds__(BLK)
anchor_pass1(const f32x4* __restrict__ a,
             f32x4* __restrict__ partial,
             float* __restrict__ ssq_arr,
             float* __restrict__ dotacc,
             unsigned* __restrict__ cnt) {
    const int col4  = blockIdx.x * BLK + threadIdx.x;   // 0..COLS4-1
    const int chunk = blockIdx.y;
    if (blockIdx.x == 0 && blockIdx.y == 0 && threadIdx.x == 0) {
        dotacc[0] = 0.f;
        cnt[0] = 0u;
    }
    const f32x4* p = a + (size_t)chunk * RPC * COLS4 + col4;

    f32x4 cs = (f32x4)(0.f);
    float ssq = 0.f;
    #pragma unroll 8
    for (int r = 0; r < RPC; ++r) {
        f32x4 v = __builtin_nontemporal_load(&p[(size_t)r * COLS4]);
        cs += v;
        ssq = fmaf(v.x, v.x, ssq);
        ssq = fmaf(v.y, v.y, ssq);
        ssq = fmaf(v.z, v.z, ssq);
        ssq = fmaf(v.w, v.w, ssq);
    }

    partial[(size_t)chunk * COLS4 + col4] = cs;

    #pragma unroll
    for (int off = 32; off > 0; off >>= 1)
        ssq += __shfl_down(ssq, off, 64);
    __shared__ float wsum[BLK / 64];
    const int lane = threadIdx.x & 63, wid = threadIdx.x >> 6;
    if (lane == 0) wsum[wid] = ssq;
    __syncthreads();
    if (threadIdx.x == 0) {
        float s = 0.f;
        #pragma unroll
        for (int w = 0; w < BLK / 64; ++w) s += wsum[w];
        ssq_arr[blockIdx.y * STRIPS + blockIdx.x] = s;
    }
}

__global__ void __launch_bounds__(BLK)
anchor_pass2(const f32x4* __restrict__ partial,
             const float* __restrict__ ssq_arr,
             float* __restrict__ dotacc,
             unsigned* __restrict__ cnt,
             float* __restrict__ out, int n_rows) {
    const int t    = threadIdx.x;
    const int jl   = t & 63;
    const int seg  = t >> 6;                // 0..3 (one wave per seg)
    const int col4 = blockIdx.x * 64 + jl;
    const int CPS  = CHUNKS / 4;            // 32 chunks per seg

    const double Cd = 2.0 / (27.712812921102035 * 64.0); // 2/(sqrt(768)*k*k)

    f32x4 cs = (f32x4)(0.f);
    #pragma unroll 8
    for (int i = 0; i < CPS; ++i)
        cs += partial[(size_t)(seg * CPS + i) * COLS4 + col4];

    __shared__ f32x4 sm[4][64];
    sm[seg][jl] = cs;
    __syncthreads();

    if (t < 64) {
        f32x4 tot = sm[0][t] + sm[1][t] + sm[2][t] + sm[3][t];
        float d = tot.x * tot.x + tot.y * tot.y
                + tot.z * tot.z + tot.w * tot.w;
        #pragma unroll
        for (int off = 32; off > 0; off >>= 1)
            d += __shfl_down(d, off, 64);
        if (t == 0) atomicAdd(dotacc, (float)(Cd * (double)d));
    }

    if (blockIdx.x == 0) {                  // uniform branch: whole block
        float s = 0.f;
        for (int i = t; i < NBLK1; i += BLK) s += ssq_arr[i];
        #pragma unroll
        for (int off = 32; off > 0; off >>= 1)
            s += __shfl_down(s, off, 64);
        __shared__ float ws2[BLK / 64];
        if ((t & 63) == 0) ws2[t >> 6] = s;
        __syncthreads();
        if (t == 0) {
            float st = 0.f;
            #pragma unroll
            for (int w = 0; w < BLK / 64; ++w) st += ws2[w];
            atomicAdd(dotacc, (float)(-Cd * (double)n_rows * (double)st));
        }
    }

    // fence-free last-block finalize (R5-proven protocol, tiny scale)
    if (t == 0) {
        asm volatile("s_waitcnt vmcnt(0)" ::: "memory");
        unsigned prev = __hip_atomic_fetch_add(cnt, 1u, __ATOMIC_RELAXED,
                                               __HIP_MEMORY_SCOPE_AGENT);
        if (prev == (unsigned)gridDim.x - 1) {
            float v = __hip_atomic_load(dotacc, __ATOMIC_RELAXED,
                                        __HIP_MEMORY_SCOPE_AGENT);
            out[0] = v;
        }
    }
}

extern "C" void kernel_launch(void* const* d_in, const int* in_sizes, int n_in,
                              void* d_out, int out_size, void* d_ws, size_t ws_size,
                              hipStream_t stream) {
    const f32x4* a = (const f32x4*)d_in[0];
    float* ws      = (float*)d_ws;
    float* out     = (float*)d_out;
    const int n_rows = in_sizes[0] / COLS;  // 8192

    f32x4* partial   = (f32x4*)ws;
    float* ssq_arr   = ws + SSQ_F;
    float* dotacc    = ws + DOTA_F;
    unsigned* cnt    = (unsigned*)(ws + CNT_F);

    dim3 grid1(STRIPS, CHUNKS);
    anchor_pass1<<<grid1, BLK, 0, stream>>>(a, partial, ssq_arr, dotacc, cnt);
    anchor_pass2<<<NBLK2, BLK, 0, stream>>>(partial, ssq_arr, dotacc, cnt,
                                            out, n_rows);
}

// Round 12
// 38.972 us; speedup vs baseline: 1.0539x; 1.0539x over previous
//
#include <hip/hip_runtime.h>

// anchors: (8192, 8, 768) fp32 = [n=8192 rows][COLS=6144 cols]
// loss = (2*dot(colsum,colsum) - 2*n*sum(a^2)) / sqrt(768) / 64
//
// R12: identical to R10 (plain loads, unroll 8) except pass1 block->work
// mapping is XCD-swizzled: flat id fid -> xcd = fid&7 owns contiguous
// chunk range [xcd*16, xcd*16+16) x 6 strips = one contiguous 25 MB
// stream per XCD (vs every XCD walking scattered strided regions).
// Heuristic only; correctness independent of the mapping.

typedef float f32x4 __attribute__((ext_vector_type(4)));

constexpr int COLS   = 6144;
constexpr int COLS4  = COLS / 4;           // 1536
constexpr int BLK    = 256;
constexpr int STRIPS = COLS4 / BLK;        // 6
constexpr int RPC    = 64;
constexpr int CHUNKS = 8192 / RPC;         // 128
constexpr int NBLK1  = STRIPS * CHUNKS;    // 768
constexpr int NBLK2  = COLS4 / 64;         // 24
constexpr int NXCD   = 8;
constexpr int PERX   = NBLK1 / NXCD;       // 96 blocks per XCD

// ws floats: partial f32x4[CHUNKS][COLS4] (3 MB) | ssq_arr[NBLK1] | dotacc | cnt
constexpr size_t PART_F = (size_t)CHUNKS * COLS4 * 4;
constexpr size_t SSQ_F  = PART_F;
constexpr size_t DOTA_F = PART_F + NBLK1;
constexpr size_t CNT_F  = DOTA_F + 1;

__global__ void __launch_bounds__(BLK)
anchor_pass1(const f32x4* __restrict__ a,
             f32x4* __restrict__ partial,
             float* __restrict__ ssq_arr,
             float* __restrict__ dotacc,
             unsigned* __restrict__ cnt) {
    // XCD-swizzled work assignment (bijective on [0,768))
    const int fid   = blockIdx.y * STRIPS + blockIdx.x;
    const int xcd   = fid & (NXCD - 1);
    const int idx   = fid >> 3;                 // 0..95
    const int chunk = xcd * (CHUNKS / NXCD) + idx / STRIPS;
    const int strip = idx % STRIPS;
    const int col4  = strip * BLK + threadIdx.x;

    if (fid == 0 && threadIdx.x == 0) {
        dotacc[0] = 0.f;
        cnt[0] = 0u;
    }
    const f32x4* p = a + (size_t)chunk * RPC * COLS4 + col4;

    f32x4 cs = (f32x4)(0.f);
    float ssq = 0.f;
    #pragma unroll 8
    for (int r = 0; r < RPC; ++r) {
        f32x4 v = p[(size_t)r * COLS4];
        cs += v;
        ssq = fmaf(v.x, v.x, ssq);
        ssq = fmaf(v.y, v.y, ssq);
        ssq = fmaf(v.z, v.z, ssq);
        ssq = fmaf(v.w, v.w, ssq);
    }

    partial[(size_t)chunk * COLS4 + col4] = cs;

    #pragma unroll
    for (int off = 32; off > 0; off >>= 1)
        ssq += __shfl_down(ssq, off, 64);
    __shared__ float wsum[BLK / 64];
    const int lane = threadIdx.x & 63, wid = threadIdx.x >> 6;
    if (lane == 0) wsum[wid] = ssq;
    __syncthreads();
    if (threadIdx.x == 0) {
        float s = 0.f;
        #pragma unroll
        for (int w = 0; w < BLK / 64; ++w) s += wsum[w];
        ssq_arr[chunk * STRIPS + strip] = s;
    }
}

__global__ void __launch_bounds__(BLK)
anchor_pass2(const f32x4* __restrict__ partial,
             const float* __restrict__ ssq_arr,
             float* __restrict__ dotacc,
             unsigned* __restrict__ cnt,
             float* __restrict__ out, int n_rows) {
    const int t    = threadIdx.x;
    const int jl   = t & 63;
    const int seg  = t >> 6;                // 0..3 (one wave per seg)
    const int col4 = blockIdx.x * 64 + jl;
    const int CPS  = CHUNKS / 4;            // 32 chunks per seg

    const double Cd = 2.0 / (27.712812921102035 * 64.0); // 2/(sqrt(768)*k*k)

    f32x4 cs = (f32x4)(0.f);
    #pragma unroll 8
    for (int i = 0; i < CPS; ++i)
        cs += partial[(size_t)(seg * CPS + i) * COLS4 + col4];

    __shared__ f32x4 sm[4][64];
    sm[seg][jl] = cs;
    __syncthreads();

    if (t < 64) {
        f32x4 tot = sm[0][t] + sm[1][t] + sm[2][t] + sm[3][t];
        float d = tot.x * tot.x + tot.y * tot.y
                + tot.z * tot.z + tot.w * tot.w;
        #pragma unroll
        for (int off = 32; off > 0; off >>= 1)
            d += __shfl_down(d, off, 64);
        if (t == 0) atomicAdd(dotacc, (float)(Cd * (double)d));
    }

    if (blockIdx.x == 0) {                  // uniform branch: whole block
        float s = 0.f;
        for (int i = t; i < NBLK1; i += BLK) s += ssq_arr[i];
        #pragma unroll
        for (int off = 32; off > 0; off >>= 1)
            s += __shfl_down(s, off, 64);
        __shared__ float ws2[BLK / 64];
        if ((t & 63) == 0) ws2[t >> 6] = s;
        __syncthreads();
        if (t == 0) {
            float st = 0.f;
            #pragma unroll
            for (int w = 0; w < BLK / 64; ++w) st += ws2[w];
            atomicAdd(dotacc, (float)(-Cd * (double)n_rows * (double)st));
        }
    }

    // fence-free last-block finalize (R5-proven protocol, tiny scale)
    if (t == 0) {
        asm volatile("s_waitcnt vmcnt(0)" ::: "memory");
        unsigned prev = __hip_atomic_fetch_add(cnt, 1u, __ATOMIC_RELAXED,
                                               __HIP_MEMORY_SCOPE_AGENT);
        if (prev == (unsigned)gridDim.x - 1) {
            float v = __hip_atomic_load(dotacc, __ATOMIC_RELAXED,
                                        __HIP_MEMORY_SCOPE_AGENT);
            out[0] = v;
        }
    }
}

extern "C" void kernel_launch(void* const* d_in, const int* in_sizes, int n_in,
                              void* d_out, int out_size, void* d_ws, size_t ws_size,
                              hipStream_t stream) {
    const f32x4* a = (const f32x4*)d_in[0];
    float* ws      = (float*)d_ws;
    float* out     = (float*)d_out;
    const int n_rows = in_sizes[0] / COLS;  // 8192

    f32x4* partial   = (f32x4*)ws;
    float* ssq_arr   = ws + SSQ_F;
    float* dotacc    = ws + DOTA_F;
    unsigned* cnt    = (unsigned*)(ws + CNT_F);

    dim3 grid1(STRIPS, CHUNKS);
    anchor_pass1<<<grid1, BLK, 0, stream>>>(a, partial, ssq_arr, dotacc, cnt);
    anchor_pass2<<<NBLK2, BLK, 0, stream>>>(partial, ssq_arr, dotacc, cnt,
                                            out, n_rows);
}